// Round 12
// baseline (188.153 us; speedup 1.0000x reference)
//
#include <hip/hip_runtime.h>
#include <hip/hip_bf16.h>

// DistPredictor on MI355X (gfx950)
//   hp  = h @ W_w.T + W_b ; hpH = hp @ H ; score[e] = ||hp[src]-hpH[dst]||^2
// One skinny GEMM C[N x 256] = h @ Wcat + bias (cols 0:128 -> hp, 128: -> hpH),
// computed transposed via mfma_f32_16x16x32_bf16 (validated round 9:
// contiguous-8 k per lane; D: col=lane&15 -> node, row=(lane>>4)*4+reg -> j).
//
// Round-9 post-mortem: total 165us; edge 44us @ 3.4TB/s (random-gather
// ceiling-ish); phase1 <43us; ~60us fixed harness overhead in timed graph.
// This round: (1) phase1 loads h fragments DIRECTLY to registers (the
// fragment pattern == the old staging-load pattern) -- no LDS, no barriers;
// ks-outer loop so every fragment is loaded exactly once per wave. Waves
// re-read the 32KB tile but L1/L2 absorb it (falsifiable: phase1 FETCH
// should stay ~52MB; if ~200MB, revert to LDS staging).
// (2) prep+pack fused into one kernel writing Wfrag directly.
// (Resubmission: rounds 10-11 were acquisition timeouts.)

#define D 128
#define BN 256
#define BM 64  // nodes per block

typedef __attribute__((ext_vector_type(8))) short bf16x8;
typedef __attribute__((ext_vector_type(4))) float f32x4;

static __device__ inline unsigned short f2bf(float x) {
  union { float f; unsigned int u; } v;
  v.f = x;
  unsigned int r = v.u + 0x7fffu + ((v.u >> 16) & 1u);  // RNE
  return (unsigned short)(r >> 16);
}

// ---------------------------------------------------------------------------
// Kernel A (fused prep+pack): 16 blocks x 256 threads. Block b = (w=b>>2,
// jt=b&3) covers j in [w*64+jt*16, +16). Thread (ks=tid>>6, lane=tid&63)
// produces ONE fragment: j = w*64+jt*16+(lane&15), k = ks*32+(lane>>4)*8+i.
//   j<128 : val[i] = Ww[j][k]                      (transpose)
//   j>=128: val[i] = sum_m Ww[m][k+i] * H[m][j-128]
// Also fills bias_cat[j] (tid<16 per block).
// ---------------------------------------------------------------------------
__global__ __launch_bounds__(256) void prep_frag_kernel(
    const float* __restrict__ Ww, const float* __restrict__ Wb,
    const float* __restrict__ H, short* __restrict__ Wfrag,
    float* __restrict__ bias_cat) {
  const int b = blockIdx.x;  // 0..15
  const int w = b >> 2;
  const int jt = b & 3;
  const int tid = threadIdx.x;
  const int ks = tid >> 6;
  const int lane = tid & 63;
  const int j = w * 64 + jt * 16 + (lane & 15);
  const int kb = ks * 32 + ((lane >> 4) << 3);

  unsigned short u[8];
  if (w < 2) {
    const float4 lo = *(const float4*)(Ww + j * D + kb);
    const float4 hi = *(const float4*)(Ww + j * D + kb + 4);
    u[0] = f2bf(lo.x); u[1] = f2bf(lo.y); u[2] = f2bf(lo.z); u[3] = f2bf(lo.w);
    u[4] = f2bf(hi.x); u[5] = f2bf(hi.y); u[6] = f2bf(hi.z); u[7] = f2bf(hi.w);
  } else {
    const int jj = j - D;
    float a0 = 0.f, a1 = 0.f, a2 = 0.f, a3 = 0.f;
    float a4 = 0.f, a5 = 0.f, a6 = 0.f, a7 = 0.f;
#pragma unroll 8
    for (int m = 0; m < D; ++m) {
      const float hm = H[m * D + jj];  // 16-lane coalesced 64B
      const float4 lo = *(const float4*)(Ww + m * D + kb);
      const float4 hi = *(const float4*)(Ww + m * D + kb + 4);
      a0 = fmaf(lo.x, hm, a0); a1 = fmaf(lo.y, hm, a1);
      a2 = fmaf(lo.z, hm, a2); a3 = fmaf(lo.w, hm, a3);
      a4 = fmaf(hi.x, hm, a4); a5 = fmaf(hi.y, hm, a5);
      a6 = fmaf(hi.z, hm, a6); a7 = fmaf(hi.w, hm, a7);
    }
    u[0] = f2bf(a0); u[1] = f2bf(a1); u[2] = f2bf(a2); u[3] = f2bf(a3);
    u[4] = f2bf(a4); u[5] = f2bf(a5); u[6] = f2bf(a6); u[7] = f2bf(a7);
  }
  const int F = ((w * 4 + jt) * 4 + ks) * 64 + lane;
  *(uint4*)(Wfrag + (size_t)F * 8) = *(const uint4*)u;

  if (tid < 16) {
    const int jb = w * 64 + jt * 16 + tid;
    float bv;
    if (w < 2) {
      bv = Wb[jb];
    } else {
      bv = 0.f;
      const int jj = jb - D;
#pragma unroll 8
      for (int m = 0; m < D; ++m) bv = fmaf(Wb[m], H[m * D + jj], bv);
    }
    bias_cat[jb] = bv;
  }
}

// ---------------------------------------------------------------------------
// Kernel B: MFMA GEMM, LDS-free. 4 waves/block; wave w owns output cols
// w*64..+63 (w<2 -> hp else hpH). Each lane loads its h fragments directly
// (2x dwordx4 at node-row addresses == exact fragment pattern), converts to
// bf16 in regs, and runs 64 MFMAs. ks-outer: every fragment loaded once.
// ---------------------------------------------------------------------------
__global__ __launch_bounds__(256, 4) void phase1_mfma(
    const float* __restrict__ h, const short* __restrict__ Wfrag,
    const float* __restrict__ bias_cat, short* __restrict__ hp,
    short* __restrict__ hpH, int n_nodes) {
  const int tid = threadIdx.x;
  const int lane = tid & 63;
  const int w = tid >> 6;
  const int base = blockIdx.x * BM;

  // ---- acc init with bias: col j = w*64 + jt*16 + (lane>>4)*4 + r ----
  f32x4 acc[4][4];  // [jt][nt]
#pragma unroll
  for (int jt = 0; jt < 4; ++jt) {
    const float4 b4 =
        *(const float4*)(bias_cat + w * 64 + jt * 16 + ((lane >> 4) << 2));
    const f32x4 bi = {b4.x, b4.y, b4.z, b4.w};
#pragma unroll
    for (int nt = 0; nt < 4; ++nt) acc[jt][nt] = bi;
  }

  const bf16x8* Wf = (const bf16x8*)Wfrag;
  const int kb = (lane >> 4) << 3;  // k offset within 32-slice

#pragma unroll
  for (int ks = 0; ks < 4; ++ks) {
    // load the 4 h fragments for this ks (one per nt), convert to bf16
    bf16x8 hf[4];
#pragma unroll
    for (int nt = 0; nt < 4; ++nt) {
      int node = base + nt * 16 + (lane & 15);
      if (node >= n_nodes) node = n_nodes - 1;  // clamp; stores guarded
      const float* hrow = h + (size_t)node * D + ks * 32 + kb;
      const float4 lo = *(const float4*)hrow;
      const float4 hi = *(const float4*)(hrow + 4);
      union { bf16x8 v; unsigned short u[8]; } pk;
      pk.u[0] = f2bf(lo.x); pk.u[1] = f2bf(lo.y);
      pk.u[2] = f2bf(lo.z); pk.u[3] = f2bf(lo.w);
      pk.u[4] = f2bf(hi.x); pk.u[5] = f2bf(hi.y);
      pk.u[6] = f2bf(hi.z); pk.u[7] = f2bf(hi.w);
      hf[nt] = pk.v;
    }
    // 16 MFMAs: stream W fragments (coalesced 16B/lane, L2-hot 64KB)
#pragma unroll
    for (int jt = 0; jt < 4; ++jt) {
      const bf16x8 wf = Wf[(((w * 4 + jt) * 4 + ks) << 6) + lane];
#pragma unroll
      for (int nt = 0; nt < 4; ++nt) {
        acc[jt][nt] = __builtin_amdgcn_mfma_f32_16x16x32_bf16(
            wf, hf[nt], acc[jt][nt], 0, 0, 0);
      }
    }
  }

  // ---- epilogue: 4 consecutive bf16 cols per lane -> 8 B store ----
  short* outb = (w < 2) ? hp : hpH;
  const int jb = (w & 1) * 64 + ((lane >> 4) << 2);
#pragma unroll
  for (int jt = 0; jt < 4; ++jt) {
#pragma unroll
    for (int nt = 0; nt < 4; ++nt) {
      const int node = base + nt * 16 + (lane & 15);
      if (node < n_nodes) {
        uint2 pk;
        pk.x = (unsigned int)f2bf(acc[jt][nt][0]) |
               ((unsigned int)f2bf(acc[jt][nt][1]) << 16);
        pk.y = (unsigned int)f2bf(acc[jt][nt][2]) |
               ((unsigned int)f2bf(acc[jt][nt][3]) << 16);
        *(uint2*)(outb + (size_t)node * D + jb + jt * 16) = pk;
      }
    }
  }
}

// ---------------------------------------------------------------------------
// Kernel C: edge scores on bf16 rows (256 B each). 16 lanes/edge, one b128
// load per array per lane; fp32 math; 4-step shuffle reduce. (validated)
// ---------------------------------------------------------------------------
__global__ __launch_bounds__(256) void edge_kernel(
    const short* __restrict__ hp, const short* __restrict__ hpH,
    const int* __restrict__ src, const int* __restrict__ dst,
    float* __restrict__ score, int n_edges) {
  const int lane = threadIdx.x & 15;
  const int e = (blockIdx.x * 256 + threadIdx.x) >> 4;
  if (e >= n_edges) return;

  const int s = src[e];
  const int d = dst[e];
  const uint4 av = *(const uint4*)(hp + (size_t)s * D + lane * 8);
  const uint4 bv = *(const uint4*)(hpH + (size_t)d * D + lane * 8);

  const unsigned int au[4] = {av.x, av.y, av.z, av.w};
  const unsigned int bu[4] = {bv.x, bv.y, bv.z, bv.w};
  float acc = 0.f;
#pragma unroll
  for (int i = 0; i < 4; ++i) {
    const float alo = __uint_as_float(au[i] << 16);
    const float ahi = __uint_as_float(au[i] & 0xffff0000u);
    const float blo = __uint_as_float(bu[i] << 16);
    const float bhi = __uint_as_float(bu[i] & 0xffff0000u);
    float t = alo - blo;
    acc = fmaf(t, t, acc);
    t = ahi - bhi;
    acc = fmaf(t, t, acc);
  }

  acc += __shfl_xor(acc, 1, 64);
  acc += __shfl_xor(acc, 2, 64);
  acc += __shfl_xor(acc, 4, 64);
  acc += __shfl_xor(acc, 8, 64);

  if (lane == 0) __builtin_nontemporal_store(acc, &score[e]);
}

// ---------------------------------------------------------------------------
extern "C" void kernel_launch(void* const* d_in, const int* in_sizes, int n_in,
                              void* d_out, int out_size, void* d_ws,
                              size_t ws_size, hipStream_t stream) {
  const float* h = (const float*)d_in[0];   // [N,128]
  const int* src = (const int*)d_in[1];     // [E] (validated int32 on device)
  const int* dst = (const int*)d_in[2];     // [E]
  const float* Ww = (const float*)d_in[3];  // [128,128]
  const float* Wb = (const float*)d_in[4];  // [128]
  const float* H = (const float*)d_in[5];   // [128,128]
  float* score = (float*)d_out;             // [E]

  const int n_nodes = in_sizes[0] / D;  // 100000
  const int n_edges = in_sizes[1];      // 600000

  // workspace carve-up (~51.3 MB; all buffers fully written before read)
  char* ws = (char*)d_ws;
  short* hp = (short*)ws;                    // N*128 bf16
  short* hpH = hp + (size_t)n_nodes * D;     // N*128 bf16
  short* Wfrag = hpH + (size_t)n_nodes * D;  // 4096 frags * 8 bf16 (64 KB)
  float* bias_cat = (float*)(Wfrag + 4096 * 8);  // 256 fp32

  prep_frag_kernel<<<dim3(16), dim3(256), 0, stream>>>(Ww, Wb, H, Wfrag,
                                                       bias_cat);

  const int nblk = (n_nodes + BM - 1) / BM;  // 1563
  phase1_mfma<<<dim3(nblk), dim3(256), 0, stream>>>(h, Wfrag, bias_cat, hp,
                                                    hpH, n_nodes);

  const int eblk = (n_edges * 16 + 255) / 256;
  edge_kernel<<<dim3(eblk), dim3(256), 0, stream>>>(hp, hpH, src, dst, score,
                                                    n_edges);
}